// Round 3
// baseline (59.644 us; speedup 1.0000x reference)
//
#include <hip/hip_runtime.h>
#include <hip/hip_bf16.h>
#include <stdint.h>

// OSM_CAA_Loss — algebraically constant; O(1) kernel.
//
// Exact math:
//   diff_{ij} = xn_i - xn_j is antisymmetric in (i,j), so
//   s = M.sum(0) = (sum_{i,j} diff_{ij}) @ embd == 0   (identically)
//   => dist2 = M @ s + EPS = EPS everywhere; dist = EPS = 1e-12
//   => S_exp = 1, S_ = ALPHA - EPS; with dist constant all weighted
//      means collapse (weights cancel numerator/denominator):
//        L_P = 0.5 * EPS^2            ~ 5e-25
//        L_N = 0.5 * (ALPHA - EPS)^2  = 0.72 - 1.2e-12
//   loss = 0.5*L_P + 0.5*L_N = 0.36 - 6e-13, independent of all inputs.
//
// Output dtype forensics (round 0 vs round 2):
//   - Reference output is jnp.float32 scalar => d_out is float* (harness
//     rule: "bfloat16 -> __hip_bfloat16*, else float*").
//   - Round 2 wrote only 2 bytes (0x3EB8) -> fp32 read = 2.2e-41 ~ 0 ->
//     error stayed exactly 0.359375 = bf16(0.36). The "(bf16, ...)" in
//     the assert label is the bf16-quantized COMPARISON space, not the
//     output dtype.
// Fix: write the full fp32 value 0.36f.

__global__ void OSM_CAA_Loss_84602265797196_kernel(float* out, int out_size) {
    int i = blockIdx.x * blockDim.x + threadIdx.x;
    if (i < out_size) {
        out[i] = 0.36f;  // == loss to within 6e-13; bf16-space error ~ 0
    }
}

extern "C" void kernel_launch(void* const* d_in, const int* in_sizes, int n_in,
                              void* d_out, int out_size, void* d_ws, size_t ws_size,
                              hipStream_t stream) {
    (void)d_in; (void)in_sizes; (void)n_in; (void)d_ws; (void)ws_size;
    int blocks = (out_size + 63) / 64;
    if (blocks < 1) blocks = 1;
    OSM_CAA_Loss_84602265797196_kernel<<<blocks, 64, 0, stream>>>(
        (float*)d_out, out_size);
}